// Round 11
// baseline (151.715 us; speedup 1.0000x reference)
//
#include <hip/hip_runtime.h>

// TensorProductContraction: fused irrep-linear + Clebsch-Gordan re-expansion.
// prep_kernel: pack x -> 12 bf16 A-panels, w -> 4 bf16 B-panels in
// mfma_f32_16x16x32_bf16 fragment lane order (26.7 MB ws).
// tp_main: per-block LDS staging of the shared mt2 A-slice (global_load_lds,
// double-buffered 24KB), R3 compute order, R3 scalar-nt epilogue (final).
// History: R3=175.7. R4 plain D/B stores: +48 (L2 thrash). R5 asm: bad.
// R6 operand swap: 318. R7/R9 LDS-staged drains: 211/212 (LDS round-trip
// costs more than TA store-lines save). R8 wide-vt L: 249 (occupancy).
// R10 A-staging: 147.4 (TA load-lines were the gap; matched prediction).
// R11: H-blocks serve 2 vtp/wave (halves H block count + staging; H VGPR 64
// stays under L's allocation -> no occupancy cost), B-loads issued before
// stage call after each barrier. L-path bit-identical.

typedef __attribute__((ext_vector_type(8))) __bf16 bf16x8;
typedef __attribute__((ext_vector_type(8))) unsigned short u16x8;
typedef __attribute__((ext_vector_type(4))) float f32x4;

#define A_V8_TOTAL (12 * 512 * 4 * 64)  // 25.2 MB
#define B_V8_TOTAL (384 * 4 * 64)       // 1.57 MB
#define P_STRIDE   (512 * 4 * 64)       // u16x8 per A panel
#define WS_NEED_BYTES ((size_t)(A_V8_TOTAL + B_V8_TOTAL) * 16)

__device__ __forceinline__ unsigned short f2bf(float f) {
  unsigned u = __builtin_bit_cast(unsigned, f);
  u = (u + 0x7FFFu + ((u >> 16) & 1u)) >> 16;  // RNE
  return (unsigned short)u;
}

__device__ __forceinline__ f32x4 mfma16(bf16x8 a, bf16x8 b, f32x4 c) {
  return __builtin_amdgcn_mfma_f32_16x16x32_bf16(a, b, c, 0, 0, 0);
}
__device__ __forceinline__ bf16x8 asbf(u16x8 v) { return __builtin_bit_cast(bf16x8, v); }
__device__ __forceinline__ void stnt(float* p, float v) { __builtin_nontemporal_store(v, p); }

// async global->LDS, 16B per lane. lds base must be wave-uniform; HW adds lane*16.
__device__ __forceinline__ void gload_lds16(const void* g, void* s) {
  __builtin_amdgcn_global_load_lds((const __attribute__((address_space(1))) void*)g,
                                   (__attribute__((address_space(3))) void*)s, 16, 0, 0);
}

// ---------------- prep: f32 -> bf16 fragment-packed panels ----------------
__global__ __launch_bounds__(256) void prep_kernel(
    const float* __restrict__ x, const float* __restrict__ w0e,
    const float* __restrict__ w1o, const float* __restrict__ w1e,
    const float* __restrict__ w2e, u16x8* __restrict__ ws) {
  int t = blockIdx.x * 256 + threadIdx.x;
  if (t < A_V8_TOTAL) {
    int l = t & 63;
    int kb = (t >> 6) & 3;
    int mt = (t >> 8) & 511;
    int p = t >> 17;
    int m = mt * 16 + (l & 15);
    int k0 = kb * 32 + (l >> 4) * 8;
    int base, d, comp;
    if (p == 0)      { base = 0;   d = 1; comp = 0;     }
    else if (p < 4)  { base = 128; d = 3; comp = p - 1; }
    else if (p < 7)  { base = 512; d = 3; comp = p - 4; }
    else             { base = 896; d = 5; comp = p - 7; }
    const float* xr = x + (size_t)m * 1536 + base + comp + k0 * d;
    u16x8 v;
#pragma unroll
    for (int e = 0; e < 8; ++e) v[e] = f2bf(xr[e * d]);
    ws[t] = v;
  } else {
    int tb = t - A_V8_TOTAL;
    if (tb >= B_V8_TOTAL) return;
    int l = tb & 63;
    int kb = (tb >> 6) & 3;
    int ci = tb >> 8;
    const float* w; int N, v0;
    if (ci < 128)      { w = w0e; N = 2048; v0 = ci * 16;         }
    else if (ci < 256) { w = w1o; N = 2048; v0 = (ci - 128) * 16; }
    else if (ci < 320) { w = w1e; N = 1024; v0 = (ci - 256) * 16; }
    else               { w = w2e; N = 1024; v0 = (ci - 320) * 16; }
    int n = v0 + (l & 15);
    int k0 = kb * 32 + (l >> 4) * 8;
    u16x8 v;
#pragma unroll
    for (int e = 0; e < 8; ++e) v[e] = f2bf(w[(size_t)(k0 + e) * N + n]);
    ws[A_V8_TOTAL + tb] = v;
  }
}

// ---------------- main fused kernel ----------------
// 6144 blocks: per mt2, 16 L-blocks (4 vt/wave-block) + 8 H-blocks (2 vtp/wave).
// acc lane map: acc[...][p][j] = y_p[m = mt2*32+mf*16+(l>>4)*4+j, v-col = l&15]
__global__ __launch_bounds__(256) void tp_main(const u16x8* __restrict__ ws,
                                               float* __restrict__ out) {
  __shared__ __align__(16) u16x8 Ash[2][1536];   // 2 x 24KB double buffer
  const int tid = threadIdx.x;
  const int l = tid & 63;
  const int wv = tid >> 6;
  const int bid = blockIdx.x;
  const int logical = (bid & 7) * 768 + (bid >> 3);  // bijective XCD swizzle (6144=8*768)
  const int mt2 = logical / 24;                      // 0..255
  const int sub = logical - mt2 * 24;                // 0..23: [0,16)=L, [16,24)=H
  const int l15 = l & 15, lhi = l >> 4;
  const u16x8* Ap = ws;
  const u16x8* Bp = ws + A_V8_TOTAL;
  const bool isL = sub < 16;
  const int nstage = isL ? 6 : 2;   // L stages 12 panels, H only panels 0..3

  const float c3  = 0.57735026918962576f;   // 1/sqrt(3)
  const float c6  = 0.40824829046386302f;   // 1/sqrt(6)
  const float c10 = 0.31622776601683794f;   // 1/sqrt(10)
  const float c30 = 0.18257418583505537f;   // 1/sqrt(30)

  // stage A-slice for kb into Ash[buf]: entry e = p*128 + mf*64 + lane
  auto stageA = [&](int kb, int buf) {
    for (int i = 0; i < nstage; ++i) {
      const int e = i * 256 + tid;
      const int p = e >> 7, mfi = (e >> 6) & 1;
      const u16x8* src = Ap + (size_t)p * P_STRIDE +
                         (((((mt2 << 1) | mfi) << 2) + kb) << 6) + (e & 63);
      gload_lds16(src, &Ash[buf][i * 256 + (tid & 192)]);  // uniform base + lane*16
    }
  };

  stageA(0, 0);

  if (isL) {
    const int vt = sub * 4 + wv;              // 0..63
    f32x4 acc[2][12];
#pragma unroll
    for (int mf = 0; mf < 2; ++mf)
#pragma unroll
      for (int p = 0; p < 12; ++p) acc[mf][p] = (f32x4)(0.0f);

    const int ci0 = vt, ci1 = 128 + vt, ci2 = 256 + vt, ci3 = 320 + vt;
    int buf = 0;
#pragma unroll
    for (int kb = 0; kb < 4; ++kb) {
      __syncthreads();                    // Ash[buf] ready (vmcnt drained)
      bf16x8 b0 = asbf(Bp[((ci0 << 2) + kb) * 64 + l]);   // issue B first
      bf16x8 b1 = asbf(Bp[((ci1 << 2) + kb) * 64 + l]);
      bf16x8 b2 = asbf(Bp[((ci2 << 2) + kb) * 64 + l]);
      bf16x8 b3 = asbf(Bp[((ci3 << 2) + kb) * 64 + l]);
      if (kb < 3) stageA(kb + 1, buf ^ 1);                // then next-tile stage
#pragma unroll
      for (int mf = 0; mf < 2; ++mf) {
        const u16x8* af = &Ash[buf][mf * 64 + l];
        acc[mf][0]  = mfma16(asbf(af[0 * 128]),  b0, acc[mf][0]);
        acc[mf][1]  = mfma16(asbf(af[1 * 128]),  b1, acc[mf][1]);
        acc[mf][2]  = mfma16(asbf(af[2 * 128]),  b1, acc[mf][2]);
        acc[mf][3]  = mfma16(asbf(af[3 * 128]),  b1, acc[mf][3]);
        acc[mf][4]  = mfma16(asbf(af[4 * 128]),  b2, acc[mf][4]);
        acc[mf][5]  = mfma16(asbf(af[5 * 128]),  b2, acc[mf][5]);
        acc[mf][6]  = mfma16(asbf(af[6 * 128]),  b2, acc[mf][6]);
        acc[mf][7]  = mfma16(asbf(af[7 * 128]),  b3, acc[mf][7]);
        acc[mf][8]  = mfma16(asbf(af[8 * 128]),  b3, acc[mf][8]);
        acc[mf][9]  = mfma16(asbf(af[9 * 128]),  b3, acc[mf][9]);
        acc[mf][10] = mfma16(asbf(af[10 * 128]), b3, acc[mf][10]);
        acc[mf][11] = mfma16(asbf(af[11 * 128]), b3, acc[mf][11]);
      }
      buf ^= 1;
    }
    // ---- epilogue: R3 verbatim (scalar nt stores, proven best) ----
    const int v5 = vt >> 1;
    const int v31 = ((vt & 1) << 4) | l15;
#pragma unroll
    for (int mf = 0; mf < 2; ++mf) {
#pragma unroll
      for (int j = 0; j < 4; ++j) {
        const int m = mt2 * 32 + mf * 16 + lhi * 4 + j;
        float* orow = out + (size_t)m * 16384;
        float* oc = orow + 4096 + v5 * 96 + v31;
        stnt(oc + 0,  acc[mf][1][j] * c3);
        stnt(oc + 32, acc[mf][2][j] * c3);
        stnt(oc + 64, acc[mf][3][j] * c3);
        const float s  = acc[mf][0][j] * c3;
        const float e0 = acc[mf][4][j], e1 = acc[mf][5][j], e2 = acc[mf][6][j];
        const float q0 = acc[mf][7][j], q1 = acc[mf][8][j];
        const float q2 = acc[mf][9][j], q3 = acc[mf][10][j], q4 = acc[mf][11][j];
        float* od = orow + 7168 + v5 * 288 + v31 * 3;
        // cg(1,1,1) = -eps/sqrt(6) (reference SVD sign)
        stnt(od + 0,   s - q2 * c30 - q4 * c10);
        stnt(od + 1,   -e2 * c6 + q1 * c10);
        stnt(od + 2,   e1 * c6 + q0 * c10);
        stnt(od + 96,  e2 * c6 + q1 * c10);
        stnt(od + 97,  s + 2.0f * q2 * c30);
        stnt(od + 98,  -e0 * c6 + q3 * c10);
        stnt(od + 192, -e1 * c6 + q0 * c10);
        stnt(od + 193, e0 * c6 + q3 * c10);
        stnt(od + 194, s - q2 * c30 + q4 * c10);
      }
    }
  } else {
    // ---- region H: 2 vtp per wave (vtp = 2*hq + vs) ----
    const int hq = (sub - 16) * 4 + wv;       // 0..31
    f32x4 acc[2][2][4];                       // [mf][vs][panel]
#pragma unroll
    for (int mf = 0; mf < 2; ++mf)
#pragma unroll
      for (int vs = 0; vs < 2; ++vs)
#pragma unroll
        for (int p = 0; p < 4; ++p) acc[mf][vs][p] = (f32x4)(0.0f);

    int buf = 0;
#pragma unroll
    for (int kb = 0; kb < 4; ++kb) {
      __syncthreads();
      bf16x8 b0[2], b1[2];
#pragma unroll
      for (int vs = 0; vs < 2; ++vs) {
        const int vtp = hq * 2 + vs;
        b0[vs] = asbf(Bp[(((64 + vtp)  << 2) + kb) * 64 + l]);
        b1[vs] = asbf(Bp[(((192 + vtp) << 2) + kb) * 64 + l]);
      }
      if (kb < 3) stageA(kb + 1, buf ^ 1);
#pragma unroll
      for (int mf = 0; mf < 2; ++mf) {
        const u16x8* af = &Ash[buf][mf * 64 + l];
        const bf16x8 a0 = asbf(af[0 * 128]);
        const bf16x8 a1 = asbf(af[1 * 128]);
        const bf16x8 a2 = asbf(af[2 * 128]);
        const bf16x8 a3 = asbf(af[3 * 128]);
#pragma unroll
        for (int vs = 0; vs < 2; ++vs) {
          acc[mf][vs][0] = mfma16(a0, b0[vs], acc[mf][vs][0]);
          acc[mf][vs][1] = mfma16(a1, b1[vs], acc[mf][vs][1]);
          acc[mf][vs][2] = mfma16(a2, b1[vs], acc[mf][vs][2]);
          acc[mf][vs][3] = mfma16(a3, b1[vs], acc[mf][vs][3]);
        }
      }
      buf ^= 1;
    }
#pragma unroll
    for (int vs = 0; vs < 2; ++vs) {
      const int vp = (hq * 2 + vs) * 16 + l15;
#pragma unroll
      for (int mf = 0; mf < 2; ++mf) {
#pragma unroll
        for (int j = 0; j < 4; ++j) {
          const int m = mt2 * 32 + mf * 16 + lhi * 4 + j;
          float* orow = out + (size_t)m * 16384;
          stnt(orow + vp, acc[mf][vs][0][j]);      // A block (cg = 1)
          float* ob = orow + 1024 + vp * 3;        // B block
          stnt(ob + 0, acc[mf][vs][1][j] * c3);
          stnt(ob + 1, acc[mf][vs][2][j] * c3);
          stnt(ob + 2, acc[mf][vs][3][j] * c3);
        }
      }
    }
  }
}

extern "C" void kernel_launch(void* const* d_in, const int* in_sizes, int n_in,
                              void* d_out, int out_size, void* d_ws, size_t ws_size,
                              hipStream_t stream) {
  if (ws_size < WS_NEED_BYTES) return;
  const float* x   = (const float*)d_in[0];
  const float* w0e = (const float*)d_in[1];
  const float* w1o = (const float*)d_in[2];
  const float* w1e = (const float*)d_in[3];
  const float* w2e = (const float*)d_in[4];
  u16x8* ws = (u16x8*)d_ws;
  float* out = (float*)d_out;

  prep_kernel<<<6528, 256, 0, stream>>>(x, w0e, w1o, w1e, w2e, ws);
  // 256 mt2 * (16 L-blocks + 8 H-blocks) = 6144 blocks
  tp_main<<<6144, 256, 0, stream>>>(ws, out);
}

// Round 12
// 146.732 us; speedup vs baseline: 1.0340x; 1.0340x over previous
//
#include <hip/hip_runtime.h>

// TensorProductContraction: fused irrep-linear + Clebsch-Gordan re-expansion.
// prep_kernel: pack x -> 12 bf16 A-panels, w -> 4 bf16 B-panels in
// mfma_f32_16x16x32_bf16 fragment lane order (26.7 MB ws).
// tp_main: per-block LDS staging of the shared mt2 A-slice (global_load_lds,
// double-buffered 24KB), R3 compute order, R3 scalar-nt epilogue with the
// D/B rho-triples compacted to {dwordx2, dword} (R12).
// History: R3=175.7. R4 plain D/B stores: +48 (L2 thrash). R5 asm dwordx3:
// miscompiled. R6 operand swap: 318. R7/R9 LDS-staged drains: 211/212.
// R8 wide-vt L: 249 (occupancy). R10 A-staging: 147.4 (TA load-lines were
// the gap). R11 H-2vtp + B-reorder: 151.7 -> reverted. R12 = R10 + store
// pairing only (9->6 D-store instrs per (mf,j); values bit-identical).

typedef __attribute__((ext_vector_type(8))) __bf16 bf16x8;
typedef __attribute__((ext_vector_type(8))) unsigned short u16x8;
typedef __attribute__((ext_vector_type(4))) float f32x4;
typedef __attribute__((ext_vector_type(2))) float f32x2;

#define A_V8_TOTAL (12 * 512 * 4 * 64)  // 25.2 MB
#define B_V8_TOTAL (384 * 4 * 64)       // 1.57 MB
#define P_STRIDE   (512 * 4 * 64)       // u16x8 per A panel
#define WS_NEED_BYTES ((size_t)(A_V8_TOTAL + B_V8_TOTAL) * 16)

__device__ __forceinline__ unsigned short f2bf(float f) {
  unsigned u = __builtin_bit_cast(unsigned, f);
  u = (u + 0x7FFFu + ((u >> 16) & 1u)) >> 16;  // RNE
  return (unsigned short)u;
}

__device__ __forceinline__ f32x4 mfma16(bf16x8 a, bf16x8 b, f32x4 c) {
  return __builtin_amdgcn_mfma_f32_16x16x32_bf16(a, b, c, 0, 0, 0);
}
__device__ __forceinline__ bf16x8 asbf(u16x8 v) { return __builtin_bit_cast(bf16x8, v); }
__device__ __forceinline__ void stnt(float* p, float v) { __builtin_nontemporal_store(v, p); }
__device__ __forceinline__ void stnt2(float* p, float a, float b) {
  f32x2 v; v[0] = a; v[1] = b;
  __builtin_nontemporal_store(v, (f32x2*)p);   // global_store_dwordx2 nt
}

// async global->LDS, 16B per lane. lds base must be wave-uniform; HW adds lane*16.
__device__ __forceinline__ void gload_lds16(const void* g, void* s) {
  __builtin_amdgcn_global_load_lds((const __attribute__((address_space(1))) void*)g,
                                   (__attribute__((address_space(3))) void*)s, 16, 0, 0);
}

// ---------------- prep: f32 -> bf16 fragment-packed panels ----------------
__global__ __launch_bounds__(256) void prep_kernel(
    const float* __restrict__ x, const float* __restrict__ w0e,
    const float* __restrict__ w1o, const float* __restrict__ w1e,
    const float* __restrict__ w2e, u16x8* __restrict__ ws) {
  int t = blockIdx.x * 256 + threadIdx.x;
  if (t < A_V8_TOTAL) {
    int l = t & 63;
    int kb = (t >> 6) & 3;
    int mt = (t >> 8) & 511;
    int p = t >> 17;
    int m = mt * 16 + (l & 15);
    int k0 = kb * 32 + (l >> 4) * 8;
    int base, d, comp;
    if (p == 0)      { base = 0;   d = 1; comp = 0;     }
    else if (p < 4)  { base = 128; d = 3; comp = p - 1; }
    else if (p < 7)  { base = 512; d = 3; comp = p - 4; }
    else             { base = 896; d = 5; comp = p - 7; }
    const float* xr = x + (size_t)m * 1536 + base + comp + k0 * d;
    u16x8 v;
#pragma unroll
    for (int e = 0; e < 8; ++e) v[e] = f2bf(xr[e * d]);
    ws[t] = v;
  } else {
    int tb = t - A_V8_TOTAL;
    if (tb >= B_V8_TOTAL) return;
    int l = tb & 63;
    int kb = (tb >> 6) & 3;
    int ci = tb >> 8;
    const float* w; int N, v0;
    if (ci < 128)      { w = w0e; N = 2048; v0 = ci * 16;         }
    else if (ci < 256) { w = w1o; N = 2048; v0 = (ci - 128) * 16; }
    else if (ci < 320) { w = w1e; N = 1024; v0 = (ci - 256) * 16; }
    else               { w = w2e; N = 1024; v0 = (ci - 320) * 16; }
    int n = v0 + (l & 15);
    int k0 = kb * 32 + (l >> 4) * 8;
    u16x8 v;
#pragma unroll
    for (int e = 0; e < 8; ++e) v[e] = f2bf(w[(size_t)(k0 + e) * N + n]);
    ws[A_V8_TOTAL + tb] = v;
  }
}

// ---------------- main fused kernel ----------------
// Block = 4 waves sharing one mt2 A-slice (staged in LDS once), each wave a
// different vt. acc[mf][p][j] = y_p[m = mt2*32+mf*16+(l>>4)*4+j, v = vt*16+(l&15)]
__global__ __launch_bounds__(256) void tp_main(const u16x8* __restrict__ ws,
                                               float* __restrict__ out) {
  __shared__ __align__(16) u16x8 Ash[2][1536];   // 2 x 24KB double buffer
  const int tid = threadIdx.x;
  const int l = tid & 63;
  const int wv = tid >> 6;
  const int bid = blockIdx.x;
  const int logical = (bid & 7) * 1024 + (bid >> 3);  // bijective XCD swizzle
  const int mt2 = logical >> 5;                       // 0..255
  const int vt = ((logical & 31) << 2) | wv;          // 0..127; region block-uniform
  const int l15 = l & 15, lhi = l >> 4;
  const u16x8* Ap = ws;
  const u16x8* Bp = ws + A_V8_TOTAL;
  const bool isL = (logical & 31) < 16;
  const int nstage = isL ? 6 : 2;   // L stages 12 panels, H only panels 0..3

  const float c3  = 0.57735026918962576f;   // 1/sqrt(3)
  const float c6  = 0.40824829046386302f;   // 1/sqrt(6)
  const float c10 = 0.31622776601683794f;   // 1/sqrt(10)
  const float c30 = 0.18257418583505537f;   // 1/sqrt(30)

  // stage A-slice for kb into Ash[buf]: entry e = p*128 + mf*64 + lane
  auto stageA = [&](int kb, int buf) {
    for (int i = 0; i < nstage; ++i) {
      const int e = i * 256 + tid;
      const int p = e >> 7, mfi = (e >> 6) & 1;
      const u16x8* src = Ap + (size_t)p * P_STRIDE +
                         (((((mt2 << 1) | mfi) << 2) + kb) << 6) + (e & 63);
      gload_lds16(src, &Ash[buf][i * 256 + (tid & 192)]);  // uniform base + lane*16
    }
  };

  stageA(0, 0);

  if (isL) {
    f32x4 acc[2][12];
#pragma unroll
    for (int mf = 0; mf < 2; ++mf)
#pragma unroll
      for (int p = 0; p < 12; ++p) acc[mf][p] = (f32x4)(0.0f);

    const int ci0 = vt, ci1 = 128 + vt, ci2 = 256 + vt, ci3 = 320 + vt;
    int buf = 0;
#pragma unroll
    for (int kb = 0; kb < 4; ++kb) {
      __syncthreads();                    // Ash[buf] ready (vmcnt drained)
      if (kb < 3) stageA(kb + 1, buf ^ 1);
      bf16x8 b0 = asbf(Bp[((ci0 << 2) + kb) * 64 + l]);
      bf16x8 b1 = asbf(Bp[((ci1 << 2) + kb) * 64 + l]);
      bf16x8 b2 = asbf(Bp[((ci2 << 2) + kb) * 64 + l]);
      bf16x8 b3 = asbf(Bp[((ci3 << 2) + kb) * 64 + l]);
#pragma unroll
      for (int mf = 0; mf < 2; ++mf) {
        const u16x8* af = &Ash[buf][mf * 64 + l];
        acc[mf][0]  = mfma16(asbf(af[0 * 128]),  b0, acc[mf][0]);
        acc[mf][1]  = mfma16(asbf(af[1 * 128]),  b1, acc[mf][1]);
        acc[mf][2]  = mfma16(asbf(af[2 * 128]),  b1, acc[mf][2]);
        acc[mf][3]  = mfma16(asbf(af[3 * 128]),  b1, acc[mf][3]);
        acc[mf][4]  = mfma16(asbf(af[4 * 128]),  b2, acc[mf][4]);
        acc[mf][5]  = mfma16(asbf(af[5 * 128]),  b2, acc[mf][5]);
        acc[mf][6]  = mfma16(asbf(af[6 * 128]),  b2, acc[mf][6]);
        acc[mf][7]  = mfma16(asbf(af[7 * 128]),  b3, acc[mf][7]);
        acc[mf][8]  = mfma16(asbf(af[8 * 128]),  b3, acc[mf][8]);
        acc[mf][9]  = mfma16(asbf(af[9 * 128]),  b3, acc[mf][9]);
        acc[mf][10] = mfma16(asbf(af[10 * 128]), b3, acc[mf][10]);
        acc[mf][11] = mfma16(asbf(af[11 * 128]), b3, acc[mf][11]);
      }
      buf ^= 1;
    }
    // ---- epilogue: R3 addresses/values; D rho-triples as {dwordx2, dword} ----
    const int v5 = vt >> 1;
    const int v31 = ((vt & 1) << 4) | l15;
#pragma unroll
    for (int mf = 0; mf < 2; ++mf) {
#pragma unroll
      for (int j = 0; j < 4; ++j) {
        const int m = mt2 * 32 + mf * 16 + lhi * 4 + j;
        float* orow = out + (size_t)m * 16384;
        float* oc = orow + 4096 + v5 * 96 + v31;
        stnt(oc + 0,  acc[mf][1][j] * c3);
        stnt(oc + 32, acc[mf][2][j] * c3);
        stnt(oc + 64, acc[mf][3][j] * c3);
        const float s  = acc[mf][0][j] * c3;
        const float e0 = acc[mf][4][j], e1 = acc[mf][5][j], e2 = acc[mf][6][j];
        const float q0 = acc[mf][7][j], q1 = acc[mf][8][j];
        const float q2 = acc[mf][9][j], q3 = acc[mf][10][j], q4 = acc[mf][11][j];
        float* od = orow + 7168 + v5 * 288 + v31 * 3;
        // cg(1,1,1) = -eps/sqrt(6) (reference SVD sign)
        stnt2(od + 0,   s - q2 * c30 - q4 * c10,    // D[0][0]
                        -e2 * c6 + q1 * c10);       // D[0][1]
        stnt (od + 2,   e1 * c6 + q0 * c10);        // D[0][2]
        stnt2(od + 96,  e2 * c6 + q1 * c10,         // D[1][0]
                        s + 2.0f * q2 * c30);       // D[1][1]
        stnt (od + 98,  -e0 * c6 + q3 * c10);       // D[1][2]
        stnt2(od + 192, -e1 * c6 + q0 * c10,        // D[2][0]
                        e0 * c6 + q3 * c10);        // D[2][1]
        stnt (od + 194, s - q2 * c30 + q4 * c10);   // D[2][2]
      }
    }
  } else {
    // ---- region H: panels 0..3 only ----
    const int vtp = vt - 64;
    f32x4 acc[2][4];
#pragma unroll
    for (int mf = 0; mf < 2; ++mf)
#pragma unroll
      for (int p = 0; p < 4; ++p) acc[mf][p] = (f32x4)(0.0f);

    const int ci0 = 64 + vtp, ci1 = 192 + vtp;
    int buf = 0;
#pragma unroll
    for (int kb = 0; kb < 4; ++kb) {
      __syncthreads();
      if (kb < 3) stageA(kb + 1, buf ^ 1);
      bf16x8 b0 = asbf(Bp[((ci0 << 2) + kb) * 64 + l]);
      bf16x8 b1 = asbf(Bp[((ci1 << 2) + kb) * 64 + l]);
#pragma unroll
      for (int mf = 0; mf < 2; ++mf) {
        const u16x8* af = &Ash[buf][mf * 64 + l];
        acc[mf][0] = mfma16(asbf(af[0 * 128]), b0, acc[mf][0]);
        acc[mf][1] = mfma16(asbf(af[1 * 128]), b1, acc[mf][1]);
        acc[mf][2] = mfma16(asbf(af[2 * 128]), b1, acc[mf][2]);
        acc[mf][3] = mfma16(asbf(af[3 * 128]), b1, acc[mf][3]);
      }
      buf ^= 1;
    }
    const int vp = vtp * 16 + l15;
#pragma unroll
    for (int mf = 0; mf < 2; ++mf) {
#pragma unroll
      for (int j = 0; j < 4; ++j) {
        const int m = mt2 * 32 + mf * 16 + lhi * 4 + j;
        float* orow = out + (size_t)m * 16384;
        stnt(orow + vp, acc[mf][0][j]);          // A block (cg = 1)
        float* ob = orow + 1024 + vp * 3;        // B block: {x2, x1}
        stnt2(ob + 0, acc[mf][1][j] * c3, acc[mf][2][j] * c3);
        stnt (ob + 2, acc[mf][3][j] * c3);
      }
    }
  }
}

extern "C" void kernel_launch(void* const* d_in, const int* in_sizes, int n_in,
                              void* d_out, int out_size, void* d_ws, size_t ws_size,
                              hipStream_t stream) {
  if (ws_size < WS_NEED_BYTES) return;
  const float* x   = (const float*)d_in[0];
  const float* w0e = (const float*)d_in[1];
  const float* w1o = (const float*)d_in[2];
  const float* w1e = (const float*)d_in[3];
  const float* w2e = (const float*)d_in[4];
  u16x8* ws = (u16x8*)d_ws;
  float* out = (float*)d_out;

  prep_kernel<<<6528, 256, 0, stream>>>(x, w0e, w1o, w1e, w2e, ws);
  tp_main<<<8192, 256, 0, stream>>>(ws, out);
}

// Round 13
// 144.831 us; speedup vs baseline: 1.0475x; 1.0131x over previous
//
#include <hip/hip_runtime.h>

// TensorProductContraction: fused irrep-linear + Clebsch-Gordan re-expansion.
// prep_kernel: pack x -> 12 bf16 A-panels, w -> 4 bf16 B-panels in
// mfma_f32_16x16x32_bf16 fragment lane order (26.7 MB ws).
// tp_main: per-block LDS staging of the shared mt2 A-slice (global_load_lds,
// 2x24KB dbuf). R13: L-waves serve 2 vt each (one ds_read feeds 2 MFMAs) ->
// L-blocks 16->8 per mt2, DS-pipe cycles and L staging fetch both halved.
// Epilogue: R3 scalar-nt pattern with {dwordx2,dword} pairing (R12), per vt-half.
// History: R3=175.7. R4 plain stores: +48. R5 asm: bad. R6 swap: 318.
// R7/R9 LDS drains: 211/212. R8 2vt w/o staging+launch_bounds(,2): 249.
// R10 A-staging: 147.4. R11 H-2vtp bundle: 151.7 (reverted). R12 store
// pairing: 146.7 (neutral -> stores not binding; DS pipe is next).

typedef __attribute__((ext_vector_type(8))) __bf16 bf16x8;
typedef __attribute__((ext_vector_type(8))) unsigned short u16x8;
typedef __attribute__((ext_vector_type(4))) float f32x4;
typedef __attribute__((ext_vector_type(2))) float f32x2;

#define A_V8_TOTAL (12 * 512 * 4 * 64)  // 25.2 MB
#define B_V8_TOTAL (384 * 4 * 64)       // 1.57 MB
#define P_STRIDE   (512 * 4 * 64)       // u16x8 per A panel
#define WS_NEED_BYTES ((size_t)(A_V8_TOTAL + B_V8_TOTAL) * 16)

__device__ __forceinline__ unsigned short f2bf(float f) {
  unsigned u = __builtin_bit_cast(unsigned, f);
  u = (u + 0x7FFFu + ((u >> 16) & 1u)) >> 16;  // RNE
  return (unsigned short)u;
}

__device__ __forceinline__ f32x4 mfma16(bf16x8 a, bf16x8 b, f32x4 c) {
  return __builtin_amdgcn_mfma_f32_16x16x32_bf16(a, b, c, 0, 0, 0);
}
__device__ __forceinline__ bf16x8 asbf(u16x8 v) { return __builtin_bit_cast(bf16x8, v); }
__device__ __forceinline__ void stnt(float* p, float v) { __builtin_nontemporal_store(v, p); }
__device__ __forceinline__ void stnt2(float* p, float a, float b) {
  f32x2 v; v[0] = a; v[1] = b;
  __builtin_nontemporal_store(v, (f32x2*)p);   // global_store_dwordx2 nt
}

// async global->LDS, 16B per lane. lds base must be wave-uniform; HW adds lane*16.
__device__ __forceinline__ void gload_lds16(const void* g, void* s) {
  __builtin_amdgcn_global_load_lds((const __attribute__((address_space(1))) void*)g,
                                   (__attribute__((address_space(3))) void*)s, 16, 0, 0);
}

// ---------------- prep: f32 -> bf16 fragment-packed panels ----------------
__global__ __launch_bounds__(256) void prep_kernel(
    const float* __restrict__ x, const float* __restrict__ w0e,
    const float* __restrict__ w1o, const float* __restrict__ w1e,
    const float* __restrict__ w2e, u16x8* __restrict__ ws) {
  int t = blockIdx.x * 256 + threadIdx.x;
  if (t < A_V8_TOTAL) {
    int l = t & 63;
    int kb = (t >> 6) & 3;
    int mt = (t >> 8) & 511;
    int p = t >> 17;
    int m = mt * 16 + (l & 15);
    int k0 = kb * 32 + (l >> 4) * 8;
    int base, d, comp;
    if (p == 0)      { base = 0;   d = 1; comp = 0;     }
    else if (p < 4)  { base = 128; d = 3; comp = p - 1; }
    else if (p < 7)  { base = 512; d = 3; comp = p - 4; }
    else             { base = 896; d = 5; comp = p - 7; }
    const float* xr = x + (size_t)m * 1536 + base + comp + k0 * d;
    u16x8 v;
#pragma unroll
    for (int e = 0; e < 8; ++e) v[e] = f2bf(xr[e * d]);
    ws[t] = v;
  } else {
    int tb = t - A_V8_TOTAL;
    if (tb >= B_V8_TOTAL) return;
    int l = tb & 63;
    int kb = (tb >> 6) & 3;
    int ci = tb >> 8;
    const float* w; int N, v0;
    if (ci < 128)      { w = w0e; N = 2048; v0 = ci * 16;         }
    else if (ci < 256) { w = w1o; N = 2048; v0 = (ci - 128) * 16; }
    else if (ci < 320) { w = w1e; N = 1024; v0 = (ci - 256) * 16; }
    else               { w = w2e; N = 1024; v0 = (ci - 320) * 16; }
    int n = v0 + (l & 15);
    int k0 = kb * 32 + (l >> 4) * 8;
    u16x8 v;
#pragma unroll
    for (int e = 0; e < 8; ++e) v[e] = f2bf(w[(size_t)(k0 + e) * N + n]);
    ws[A_V8_TOTAL + tb] = v;
  }
}

// panel -> B-class {0:0e, 1:1o, 2:1e, 3:2e}
#define CLS_OF(p) ((p) == 0 ? 0 : (p) < 4 ? 1 : (p) < 7 ? 2 : 3)

// ---------------- main fused kernel ----------------
// Per mt2: 8 L-blocks (4 waves x 2 vt) + 16 H-blocks (4 waves x 1 vtp) = 24.
// acc lane map: acc[...][p][j] = y_p[m = mt2*32+mf*16+(l>>4)*4+j, v-col = l&15]
__global__ __launch_bounds__(256) void tp_main(const u16x8* __restrict__ ws,
                                               float* __restrict__ out) {
  __shared__ __align__(16) u16x8 Ash[2][1536];   // 2 x 24KB double buffer
  const int tid = threadIdx.x;
  const int l = tid & 63;
  const int wv = tid >> 6;
  const int bid = blockIdx.x;
  const int logical = (bid & 7) * 768 + (bid >> 3);  // 6144 = 8*768, bijective
  const int mt2 = logical / 24;                      // 0..255
  const int sub = logical - mt2 * 24;                // 0..23: [0,8)=L, [8,24)=H
  const int l15 = l & 15, lhi = l >> 4;
  const u16x8* Ap = ws;
  const u16x8* Bp = ws + A_V8_TOTAL;
  const bool isL = sub < 8;
  const int nstage = isL ? 6 : 2;   // L stages 12 panels, H only panels 0..3

  const float c3  = 0.57735026918962576f;   // 1/sqrt(3)
  const float c6  = 0.40824829046386302f;   // 1/sqrt(6)
  const float c10 = 0.31622776601683794f;   // 1/sqrt(10)
  const float c30 = 0.18257418583505537f;   // 1/sqrt(30)

  // stage A-slice for kb into Ash[buf]: entry e = p*128 + mf*64 + lane
  auto stageA = [&](int kb, int buf) {
    for (int i = 0; i < nstage; ++i) {
      const int e = i * 256 + tid;
      const int p = e >> 7, mfi = (e >> 6) & 1;
      const u16x8* src = Ap + (size_t)p * P_STRIDE +
                         (((((mt2 << 1) | mfi) << 2) + kb) << 6) + (e & 63);
      gload_lds16(src, &Ash[buf][i * 256 + (tid & 192)]);  // uniform base + lane*16
    }
  };

  stageA(0, 0);

  if (isL) {
    const int vq = sub * 4 + wv;              // 0..31; serves vt = 2vq, 2vq+1
    f32x4 acc[2][2][12];                      // [mf][vh][panel]
#pragma unroll
    for (int mf = 0; mf < 2; ++mf)
#pragma unroll
      for (int vh = 0; vh < 2; ++vh)
#pragma unroll
        for (int p = 0; p < 12; ++p) acc[mf][vh][p] = (f32x4)(0.0f);

    int buf = 0;
#pragma unroll
    for (int kb = 0; kb < 4; ++kb) {
      __syncthreads();                    // Ash[buf] ready (vmcnt drained)
      if (kb < 3) stageA(kb + 1, buf ^ 1);
      bf16x8 b[2][4];
#pragma unroll
      for (int vh = 0; vh < 2; ++vh) {
        const int vt = vq * 2 + vh;
        b[vh][0] = asbf(Bp[(((vt)       << 2) + kb) * 64 + l]);
        b[vh][1] = asbf(Bp[(((128 + vt) << 2) + kb) * 64 + l]);
        b[vh][2] = asbf(Bp[(((256 + vt) << 2) + kb) * 64 + l]);
        b[vh][3] = asbf(Bp[(((320 + vt) << 2) + kb) * 64 + l]);
      }
#pragma unroll
      for (int mf = 0; mf < 2; ++mf) {
        const u16x8* af = &Ash[buf][mf * 64 + l];
#pragma unroll
        for (int p = 0; p < 12; ++p) {
          const bf16x8 a = asbf(af[p * 128]);    // one ds_read feeds 2 MFMAs
          acc[mf][0][p] = mfma16(a, b[0][CLS_OF(p)], acc[mf][0][p]);
          acc[mf][1][p] = mfma16(a, b[1][CLS_OF(p)], acc[mf][1][p]);
        }
      }
      buf ^= 1;
    }
    // ---- epilogue: R12 pattern per vt-half. v5 = vq; v31 = (vh<<4)|l15 ----
    const int v5 = vq;
#pragma unroll
    for (int vh = 0; vh < 2; ++vh) {
      const int v31 = (vh << 4) | l15;
#pragma unroll
      for (int mf = 0; mf < 2; ++mf) {
#pragma unroll
        for (int j = 0; j < 4; ++j) {
          const int m = mt2 * 32 + mf * 16 + lhi * 4 + j;
          float* orow = out + (size_t)m * 16384;
          float* oc = orow + 4096 + v5 * 96 + v31;
          stnt(oc + 0,  acc[mf][vh][1][j] * c3);
          stnt(oc + 32, acc[mf][vh][2][j] * c3);
          stnt(oc + 64, acc[mf][vh][3][j] * c3);
          const float s  = acc[mf][vh][0][j] * c3;
          const float e0 = acc[mf][vh][4][j], e1 = acc[mf][vh][5][j], e2 = acc[mf][vh][6][j];
          const float q0 = acc[mf][vh][7][j], q1 = acc[mf][vh][8][j];
          const float q2 = acc[mf][vh][9][j], q3 = acc[mf][vh][10][j], q4 = acc[mf][vh][11][j];
          float* od = orow + 7168 + v5 * 288 + v31 * 3;
          // cg(1,1,1) = -eps/sqrt(6) (reference SVD sign)
          stnt2(od + 0,   s - q2 * c30 - q4 * c10,    // D[0][0]
                          -e2 * c6 + q1 * c10);       // D[0][1]
          stnt (od + 2,   e1 * c6 + q0 * c10);        // D[0][2]
          stnt2(od + 96,  e2 * c6 + q1 * c10,         // D[1][0]
                          s + 2.0f * q2 * c30);       // D[1][1]
          stnt (od + 98,  -e0 * c6 + q3 * c10);       // D[1][2]
          stnt2(od + 192, -e1 * c6 + q0 * c10,        // D[2][0]
                          e0 * c6 + q3 * c10);        // D[2][1]
          stnt (od + 194, s - q2 * c30 + q4 * c10);   // D[2][2]
        }
      }
    }
  } else {
    // ---- region H (R12 verbatim): 1 vtp/wave, panels 0..3 ----
    const int vtp = (sub - 8) * 4 + wv;       // 0..63
    f32x4 acc[2][4];
#pragma unroll
    for (int mf = 0; mf < 2; ++mf)
#pragma unroll
      for (int p = 0; p < 4; ++p) acc[mf][p] = (f32x4)(0.0f);

    const int ci0 = 64 + vtp, ci1 = 192 + vtp;
    int buf = 0;
#pragma unroll
    for (int kb = 0; kb < 4; ++kb) {
      __syncthreads();
      if (kb < 3) stageA(kb + 1, buf ^ 1);
      bf16x8 b0 = asbf(Bp[((ci0 << 2) + kb) * 64 + l]);
      bf16x8 b1 = asbf(Bp[((ci1 << 2) + kb) * 64 + l]);
#pragma unroll
      for (int mf = 0; mf < 2; ++mf) {
        const u16x8* af = &Ash[buf][mf * 64 + l];
        acc[mf][0] = mfma16(asbf(af[0 * 128]), b0, acc[mf][0]);
        acc[mf][1] = mfma16(asbf(af[1 * 128]), b1, acc[mf][1]);
        acc[mf][2] = mfma16(asbf(af[2 * 128]), b1, acc[mf][2]);
        acc[mf][3] = mfma16(asbf(af[3 * 128]), b1, acc[mf][3]);
      }
      buf ^= 1;
    }
    const int vp = vtp * 16 + l15;
#pragma unroll
    for (int mf = 0; mf < 2; ++mf) {
#pragma unroll
      for (int j = 0; j < 4; ++j) {
        const int m = mt2 * 32 + mf * 16 + lhi * 4 + j;
        float* orow = out + (size_t)m * 16384;
        stnt(orow + vp, acc[mf][0][j]);          // A block (cg = 1)
        float* ob = orow + 1024 + vp * 3;        // B block: {x2, x1}
        stnt2(ob + 0, acc[mf][1][j] * c3, acc[mf][2][j] * c3);
        stnt (ob + 2, acc[mf][3][j] * c3);
      }
    }
  }
}

extern "C" void kernel_launch(void* const* d_in, const int* in_sizes, int n_in,
                              void* d_out, int out_size, void* d_ws, size_t ws_size,
                              hipStream_t stream) {
  if (ws_size < WS_NEED_BYTES) return;
  const float* x   = (const float*)d_in[0];
  const float* w0e = (const float*)d_in[1];
  const float* w1o = (const float*)d_in[2];
  const float* w1e = (const float*)d_in[3];
  const float* w2e = (const float*)d_in[4];
  u16x8* ws = (u16x8*)d_ws;
  float* out = (float*)d_out;

  prep_kernel<<<6528, 256, 0, stream>>>(x, w0e, w1o, w1e, w2e, ws);
  // 256 mt2 * (8 L-blocks + 16 H-blocks) = 6144 blocks
  tp_main<<<6144, 256, 0, stream>>>(ws, out);
}